// Round 1
// baseline (385.758 us; speedup 1.0000x reference)
//
#include <hip/hip_runtime.h>

// ImplicitNet fused MLP, bf16 MFMA version.
// Layers: IN=[51,256x8] OUT=[256,256,256,253,256,256,256,256,257], softplus(beta=100)
// on layers 0..7, skip-concat(x_in)*1/sqrt(2) feeding layer 4, cond concat at layer 0.
//
// d_ws layout: bf16 weights, fragment-major. Per layer: chunks of 64 lanes x 8 bf16,
// chunk(ntile,ktile,lane) holds W[ntile*16 + (lane&15)][ktile*32 + (lane>>4)*8 + j].
// Padding: L0 K 51->64, L3 N 253->256 (zero rows), L8 N 257->272 (zero rows).
// Requires ws_size >= 1,089,536 bytes.

typedef __attribute__((ext_vector_type(8))) short bf16x8;
typedef __attribute__((ext_vector_type(4))) float f32x4;

#define PPTS 50000

__device__ __forceinline__ short f2bf(float f) {
    union { float f; unsigned u; } v; v.f = f;
    unsigned r = v.u + 0x7fffu + ((v.u >> 16) & 1u);   // RTNE (inputs finite)
    return (short)(r >> 16);
}

// softplus(100x)/100 = max(x,0) + log1p(exp(-100|x|))/100
__device__ __forceinline__ float softplus100(float x) {
    float e = __builtin_amdgcn_exp2f(fabsf(x) * -144.26950408889634f); // exp(-100|x|)
    float l = __builtin_amdgcn_logf(1.0f + e);                          // log2(1+e)
    return fmaxf(x, 0.0f) + 0.0069314718055994531f * l;                 // + ln2/100*log2
}

// LDS activation tile: [64 rows][256 cols] bf16, row stride 512B,
// XOR swizzle on byte bits [4:6] by (row&7) to kill the stride-512 bank conflict (G4).
__device__ __forceinline__ short* xaddr(short* base, int row, int col) {
    int off = ((row << 9) + (col << 1)) ^ ((row & 7) << 4);
    return (short*)((char*)base + off);
}
__device__ __forceinline__ const short* xaddrc(const short* base, int row, int col) {
    int off = ((row << 9) + (col << 1)) ^ ((row & 7) << 4);
    return (const short*)((const char*)base + off);
}

// ---------------- weight prep: f32 row-major -> bf16 fragment-major ----------------
__global__ void prep_kernel(
    const float* __restrict__ W0, const float* __restrict__ W1, const float* __restrict__ W2,
    const float* __restrict__ W3, const float* __restrict__ W4, const float* __restrict__ W5,
    const float* __restrict__ W6, const float* __restrict__ W7, const float* __restrict__ W8,
    short* __restrict__ wbf)
{
    const int gid = blockIdx.x * blockDim.x + threadIdx.x;
    if (gid >= 68096) return;                       // total 16B chunks
    int l, cid; const float* Wsrc;
    if      (gid <  2048) { l = 0; cid = gid;         Wsrc = W0; }
    else if (gid < 10240) { l = 1; cid = gid -  2048; Wsrc = W1; }
    else if (gid < 18432) { l = 2; cid = gid - 10240; Wsrc = W2; }
    else if (gid < 26624) { l = 3; cid = gid - 18432; Wsrc = W3; }
    else if (gid < 34816) { l = 4; cid = gid - 26624; Wsrc = W4; }
    else if (gid < 43008) { l = 5; cid = gid - 34816; Wsrc = W5; }
    else if (gid < 51200) { l = 6; cid = gid - 43008; Wsrc = W6; }
    else if (gid < 59392) { l = 7; cid = gid - 51200; Wsrc = W7; }
    else                  { l = 8; cid = gid - 59392; Wsrc = W8; }
    const int NR   = (l == 3) ? 253 : ((l == 8) ? 257 : 256);
    const int KR   = (l == 0) ? 51 : 256;
    const int klog = (l == 0) ? 1 : 3;              // ktiles = Kpad/32 = 2 or 8
    const int lane  = cid & 63;
    const int tile  = cid >> 6;
    const int ntile = tile >> klog;
    const int ktile = tile & ((1 << klog) - 1);
    const int n  = ntile * 16 + (lane & 15);
    const int k0 = ktile * 32 + ((lane >> 4) << 3);
    bf16x8 v;
#pragma unroll
    for (int j = 0; j < 8; ++j) {
        int k = k0 + j;
        float f = (n < NR && k < KR) ? Wsrc[n * KR + k] : 0.0f;
        v[j] = f2bf(f);
    }
    ((bf16x8*)wbf)[gid] = v;
}

// ---------------- one hidden layer: LDS(src) @ W^T -> softplus -> LDS(dst) ----------
// MODE 0: normal hidden layer. MODE 1: layer 3 (N=253, scale by 1/sqrt2 for skip).
template<int KSTEPS, int MODE>
__device__ __forceinline__ void layer_fwd(const short* src, short* dst,
    const bf16x8* __restrict__ wl, const float* __restrict__ bias, int lane, int wid)
{
    const int mrow = lane & 15;
    const int kg   = (lane >> 4) << 3;
    f32x4 acc[4][4] = {};
#pragma unroll 2
    for (int ks = 0; ks < KSTEPS; ++ks) {
        bf16x8 a[4], b[4];
#pragma unroll
        for (int mi = 0; mi < 4; ++mi)
            a[mi] = *(const bf16x8*)xaddrc(src, mi * 16 + mrow, ks * 32 + kg);
#pragma unroll
        for (int ni = 0; ni < 4; ++ni)
            b[ni] = wl[((wid * 4 + ni) * KSTEPS + ks) * 64 + lane];
#pragma unroll
        for (int mi = 0; mi < 4; ++mi)
#pragma unroll
            for (int ni = 0; ni < 4; ++ni)
                acc[mi][ni] = __builtin_amdgcn_mfma_f32_16x16x32_bf16(
                    a[mi], b[ni], acc[mi][ni], 0, 0, 0);
    }
    const int rbase = (lane >> 4) << 2;
#pragma unroll
    for (int ni = 0; ni < 4; ++ni) {
        const int col = wid * 64 + ni * 16 + mrow;
        const float bv = bias[(MODE == 1) ? (col < 253 ? col : 252) : col];
#pragma unroll
        for (int mi = 0; mi < 4; ++mi) {
#pragma unroll
            for (int r = 0; r < 4; ++r) {
                float y = acc[mi][ni][r] + bv;
                float s = softplus100(y);
                if (MODE == 1) s *= 0.70710678f;
                if (MODE != 1 || col < 253)
                    *xaddr(dst, mi * 16 + rbase + r, col) = f2bf(s);
            }
        }
    }
}

// ---------------- fused network kernel: 64 points per block ------------------------
__global__ __launch_bounds__(256, 2) void net_kernel(
    const float* __restrict__ xin, const float* __restrict__ cond,
    const bf16x8* __restrict__ W,
    const float* __restrict__ b0, const float* __restrict__ b1, const float* __restrict__ b2,
    const float* __restrict__ b3, const float* __restrict__ b4, const float* __restrict__ b5,
    const float* __restrict__ b6, const float* __restrict__ b7, const float* __restrict__ b8,
    float* __restrict__ out)
{
    __shared__ short xb0[64 * 256];
    __shared__ short xb1[64 * 256];
    const int t    = threadIdx.x;
    const int pt0  = blockIdx.x * 64;
    const int lane = t & 63;
    const int wid  = t >> 6;

    // build X0 = [x(3) | cond(48) | zeros(13)] per point, bf16 into LDS
    {
        const int row   = t >> 2;
        const int c0    = (t & 3) << 4;
        const int point = pt0 + row;
        const int batch = point / PPTS;
        const float* xp = xin + point * 3;
        const float* cp = cond + batch * 48;
#pragma unroll
        for (int i = 0; i < 16; ++i) {
            int c = c0 + i;
            float v = (c < 3) ? xp[c] : ((c < 51) ? cp[c - 3] : 0.0f);
            *xaddr(xb0, row, c) = f2bf(v);
        }
    }
    __syncthreads();

    layer_fwd<2, 0>(xb0, xb1, W +     0, b0, lane, wid); __syncthreads();
    layer_fwd<8, 0>(xb1, xb0, W +  2048, b1, lane, wid); __syncthreads();
    layer_fwd<8, 0>(xb0, xb1, W + 10240, b2, lane, wid); __syncthreads();
    layer_fwd<8, 1>(xb1, xb0, W + 18432, b3, lane, wid);
    // skip connection: cols 253..255 of layer-4 input = x_in * 1/sqrt2
    if (t < 64) {
        const int point = pt0 + t;
#pragma unroll
        for (int c = 0; c < 3; ++c)
            *xaddr(xb0, t, 253 + c) = f2bf(xin[point * 3 + c] * 0.70710678f);
    }
    __syncthreads();
    layer_fwd<8, 0>(xb0, xb1, W + 26624, b4, lane, wid); __syncthreads();
    layer_fwd<8, 0>(xb1, xb0, W + 34816, b5, lane, wid); __syncthreads();
    layer_fwd<8, 0>(xb0, xb1, W + 43008, b6, lane, wid); __syncthreads();
    layer_fwd<8, 0>(xb1, xb0, W + 51200, b7, lane, wid); __syncthreads();

    // layer 8: N=257, no activation, f32 store to d_out. Wave 0 also computes the
    // extra 16-col tile (only col 256 is real).
    {
        const bf16x8* wl = W + 59392;
        const int mrow = lane & 15;
        const int kg   = (lane >> 4) << 3;
        f32x4 acc[4][4] = {};
        f32x4 acc2[4]   = {};
#pragma unroll 2
        for (int ks = 0; ks < 8; ++ks) {
            bf16x8 a[4], b[4];
#pragma unroll
            for (int mi = 0; mi < 4; ++mi)
                a[mi] = *(const bf16x8*)xaddrc(xb0, mi * 16 + mrow, ks * 32 + kg);
#pragma unroll
            for (int ni = 0; ni < 4; ++ni)
                b[ni] = wl[((wid * 4 + ni) * 8 + ks) * 64 + lane];
#pragma unroll
            for (int mi = 0; mi < 4; ++mi)
#pragma unroll
                for (int ni = 0; ni < 4; ++ni)
                    acc[mi][ni] = __builtin_amdgcn_mfma_f32_16x16x32_bf16(
                        a[mi], b[ni], acc[mi][ni], 0, 0, 0);
            if (wid == 0) {
                bf16x8 b2 = wl[(128 + ks) * 64 + lane];
#pragma unroll
                for (int mi = 0; mi < 4; ++mi)
                    acc2[mi] = __builtin_amdgcn_mfma_f32_16x16x32_bf16(
                        a[mi], b2, acc2[mi], 0, 0, 0);
            }
        }
        const int rbase = (lane >> 4) << 2;
#pragma unroll
        for (int ni = 0; ni < 4; ++ni) {
            const int col = wid * 64 + ni * 16 + mrow;
            const float bv = b8[col];
#pragma unroll
            for (int mi = 0; mi < 4; ++mi)
#pragma unroll
                for (int r = 0; r < 4; ++r)
                    out[(pt0 + mi * 16 + rbase + r) * 257 + col] = acc[mi][ni][r] + bv;
        }
        if (wid == 0 && mrow == 0) {
            const float bv = b8[256];
#pragma unroll
            for (int mi = 0; mi < 4; ++mi)
#pragma unroll
                for (int r = 0; r < 4; ++r)
                    out[(pt0 + mi * 16 + rbase + r) * 257 + 256] = acc2[mi][r] + bv;
        }
    }
}

extern "C" void kernel_launch(void* const* d_in, const int* in_sizes, int n_in,
                              void* d_out, int out_size, void* d_ws, size_t ws_size,
                              hipStream_t stream)
{
    const float* xin  = (const float*)d_in[0];
    const float* cond = (const float*)d_in[1];
    const float* Wp[9]; const float* bp[9];
    for (int l = 0; l < 9; ++l) { Wp[l] = (const float*)d_in[2 + 2 * l]; bp[l] = (const float*)d_in[3 + 2 * l]; }
    short* wbf = (short*)d_ws;   // needs 1,089,536 B

    prep_kernel<<<dim3(266), dim3(256), 0, stream>>>(
        Wp[0], Wp[1], Wp[2], Wp[3], Wp[4], Wp[5], Wp[6], Wp[7], Wp[8], wbf);
    net_kernel<<<dim3(3125), dim3(256), 0, stream>>>(
        xin, cond, (const bf16x8*)wbf,
        bp[0], bp[1], bp[2], bp[3], bp[4], bp[5], bp[6], bp[7], bp[8],
        (float*)d_out);
}

// Round 2
// 316.050 us; speedup vs baseline: 1.2206x; 1.2206x over previous
//
#include <hip/hip_runtime.h>

// ImplicitNet fused MLP, bf16 MFMA, swapped-operand (D = W·X^T) version.
// 512 threads/block (8 waves), 64 points/block, each wave owns 32 output cols.
// LDS: two 64x256 bf16 activation buffers (64 KB) -> 2 blocks/CU = 16 waves/CU.
//
// d_ws: bf16 weights, fragment-major (same layout as R1): chunk(ntile,ktile,lane)
// holds W[ntile*16 + (lane&15)][ktile*32 + (lane>>4)*8 + j]. Serves as the MFMA
// A-operand now (A/B lane maps are symmetric for 16x16x32 bf16).
// Padding: L0 K 51->64, L3 N 253->256, L8 N 257->272. ws >= 1,089,536 B.

typedef __attribute__((ext_vector_type(8))) short bf16x8;
typedef __attribute__((ext_vector_type(4))) short s16x4;
typedef __attribute__((ext_vector_type(4))) float f32x4;

#define PPTS 50000

__device__ __forceinline__ short f2bf(float f) {
    union { float f; unsigned u; } v; v.f = f;
    unsigned r = v.u + 0x7fffu + ((v.u >> 16) & 1u);   // RTNE (finite inputs)
    return (short)(r >> 16);
}

// softplus(100x)/100 = max(x,0) + log1p(exp(-100|x|))/100
__device__ __forceinline__ float softplus100(float x) {
    float e = __builtin_amdgcn_exp2f(fabsf(x) * -144.26950408889634f); // exp(-100|x|)
    float l = __builtin_amdgcn_logf(1.0f + e);                          // log2(1+e)
    return fmaxf(x, 0.0f) + 0.0069314718055994531f * l;                 // + ln2/100*log2
}

// LDS tile [64][256] bf16, row stride 512B, XOR swizzle byte^=(row&7)<<4 (G4).
// Swizzle is a multiple of 16 -> preserves 8B/16B alignment of b64/b128 accesses.
__device__ __forceinline__ short* xaddr(short* base, int row, int col) {
    int off = ((row << 9) + (col << 1)) ^ ((row & 7) << 4);
    return (short*)((char*)base + off);
}
__device__ __forceinline__ const short* xaddrc(const short* base, int row, int col) {
    int off = ((row << 9) + (col << 1)) ^ ((row & 7) << 4);
    return (const short*)((const char*)base + off);
}

// ---------------- weight prep: f32 row-major -> bf16 fragment-major ----------------
__global__ void prep_kernel(
    const float* __restrict__ W0, const float* __restrict__ W1, const float* __restrict__ W2,
    const float* __restrict__ W3, const float* __restrict__ W4, const float* __restrict__ W5,
    const float* __restrict__ W6, const float* __restrict__ W7, const float* __restrict__ W8,
    short* __restrict__ wbf)
{
    const int gid = blockIdx.x * blockDim.x + threadIdx.x;
    if (gid >= 68096) return;                       // total 16B chunks
    int l, cid; const float* Wsrc;
    if      (gid <  2048) { l = 0; cid = gid;         Wsrc = W0; }
    else if (gid < 10240) { l = 1; cid = gid -  2048; Wsrc = W1; }
    else if (gid < 18432) { l = 2; cid = gid - 10240; Wsrc = W2; }
    else if (gid < 26624) { l = 3; cid = gid - 18432; Wsrc = W3; }
    else if (gid < 34816) { l = 4; cid = gid - 26624; Wsrc = W4; }
    else if (gid < 43008) { l = 5; cid = gid - 34816; Wsrc = W5; }
    else if (gid < 51200) { l = 6; cid = gid - 43008; Wsrc = W6; }
    else if (gid < 59392) { l = 7; cid = gid - 51200; Wsrc = W7; }
    else                  { l = 8; cid = gid - 59392; Wsrc = W8; }
    const int NR   = (l == 3) ? 253 : ((l == 8) ? 257 : 256);
    const int KR   = (l == 0) ? 51 : 256;
    const int klog = (l == 0) ? 1 : 3;              // ktiles = Kpad/32 = 2 or 8
    const int lane  = cid & 63;
    const int tile  = cid >> 6;
    const int ntile = tile >> klog;
    const int ktile = tile & ((1 << klog) - 1);
    const int n  = ntile * 16 + (lane & 15);
    const int k0 = ktile * 32 + ((lane >> 4) << 3);
    bf16x8 v;
#pragma unroll
    for (int j = 0; j < 8; ++j) {
        int k = k0 + j;
        float f = (n < NR && k < KR) ? Wsrc[n * KR + k] : 0.0f;
        v[j] = f2bf(f);
    }
    ((bf16x8*)wbf)[gid] = v;
}

// ---------------- one hidden layer: W @ LDS(src)^T -> softplus -> LDS(dst) ----------
// Output lands transposed: thread holds 4 CONSECUTIVE out-cols for one point row
// -> b64 LDS writes, float4 bias loads.
// MODE 0: normal. MODE 1: layer 3 (N=253, scale 1/sqrt2 for skip).
template<int KSTEPS, int MODE>
__device__ __forceinline__ void layer_fwd(const short* src, short* dst,
    const bf16x8* __restrict__ wl, const float* __restrict__ bias, int lane, int wid)
{
    const int prow = lane & 15;
    const int kg   = (lane >> 4) << 3;
    const int rb4  = (lane >> 4) << 2;
    f32x4 bv[2];
#pragma unroll
    for (int nii = 0; nii < 2; ++nii) {              // hoisted: hides under MFMA
        const int cb = (wid * 2 + nii) * 16 + rb4;
        if (MODE == 1 && cb == 252) { f32x4 t = {bias[252], 0.f, 0.f, 0.f}; bv[nii] = t; }
        else bv[nii] = *(const f32x4*)(bias + cb);
    }
    f32x4 acc[4][2] = {};
#pragma unroll 2
    for (int ks = 0; ks < KSTEPS; ++ks) {
        bf16x8 a[2], b[4];
#pragma unroll
        for (int nii = 0; nii < 2; ++nii)
            a[nii] = wl[((wid * 2 + nii) * KSTEPS + ks) * 64 + lane];
#pragma unroll
        for (int mi = 0; mi < 4; ++mi)
            b[mi] = *(const bf16x8*)xaddrc(src, mi * 16 + prow, ks * 32 + kg);
#pragma unroll
        for (int mi = 0; mi < 4; ++mi)
#pragma unroll
            for (int nii = 0; nii < 2; ++nii)
                acc[mi][nii] = __builtin_amdgcn_mfma_f32_16x16x32_bf16(
                    a[nii], b[mi], acc[mi][nii], 0, 0, 0);
    }
#pragma unroll
    for (int nii = 0; nii < 2; ++nii) {
        const int cb = (wid * 2 + nii) * 16 + rb4;
#pragma unroll
        for (int mi = 0; mi < 4; ++mi) {
            s16x4 p;
#pragma unroll
            for (int r = 0; r < 4; ++r) {
                float s = softplus100(acc[mi][nii][r] + bv[nii][r]);
                if (MODE == 1) s *= 0.70710678f;
                p[r] = f2bf(s);
            }
            if (MODE == 1 && cb == 252)
                *xaddr(dst, mi * 16 + prow, 252) = p[0];   // cols 253-255: skip slots
            else
                *(s16x4*)xaddr(dst, mi * 16 + prow, cb) = p;
        }
    }
}

// ---------------- fused network kernel: 64 points, 8 waves ------------------------
__global__ __launch_bounds__(512, 4) void net_kernel(
    const float* __restrict__ xin, const float* __restrict__ cond,
    const bf16x8* __restrict__ W,
    const float* __restrict__ b0, const float* __restrict__ b1, const float* __restrict__ b2,
    const float* __restrict__ b3, const float* __restrict__ b4, const float* __restrict__ b5,
    const float* __restrict__ b6, const float* __restrict__ b7, const float* __restrict__ b8,
    float* __restrict__ out)
{
    __shared__ short xb0[64 * 256];
    __shared__ short xb1[64 * 256];
    const int t    = threadIdx.x;
    const int pt0  = blockIdx.x * 64;
    const int lane = t & 63;
    const int wid  = t >> 6;

    // hoist skip-connection values (used after layer 3)
    float sk[3] = {0.f, 0.f, 0.f};
    if (t < 64) {
#pragma unroll
        for (int c = 0; c < 3; ++c)
            sk[c] = xin[(pt0 + t) * 3 + c] * 0.70710678f;
    }

    // build X0 = [x(3) | cond(48) | zeros(13..63)] per point, bf16 into LDS
    {
        const int row   = t >> 3;           // 0..63
        const int c0    = (t & 7) << 3;     // 0..56
        const int point = pt0 + row;
        const int batch = point / PPTS;
        const float* xp = xin + point * 3;
        const float* cp = cond + batch * 48;
        bf16x8 v;
#pragma unroll
        for (int i = 0; i < 8; ++i) {
            int c = c0 + i;
            float f = (c < 3) ? xp[c] : ((c < 51) ? cp[c - 3] : 0.0f);
            v[i] = f2bf(f);
        }
        *(bf16x8*)xaddr(xb0, row, c0) = v;
    }
    __syncthreads();

    layer_fwd<2, 0>(xb0, xb1, W +     0, b0, lane, wid); __syncthreads();
    layer_fwd<8, 0>(xb1, xb0, W +  2048, b1, lane, wid); __syncthreads();
    layer_fwd<8, 0>(xb0, xb1, W + 10240, b2, lane, wid); __syncthreads();
    layer_fwd<8, 1>(xb1, xb0, W + 18432, b3, lane, wid);
    // skip connection: cols 253..255 of layer-4 input = x_in * 1/sqrt2
    if (t < 64) {
#pragma unroll
        for (int c = 0; c < 3; ++c)
            *xaddr(xb0, t, 253 + c) = f2bf(sk[c]);
    }
    __syncthreads();
    layer_fwd<8, 0>(xb0, xb1, W + 26624, b4, lane, wid); __syncthreads();
    layer_fwd<8, 0>(xb1, xb0, W + 34816, b5, lane, wid); __syncthreads();
    layer_fwd<8, 0>(xb0, xb1, W + 43008, b6, lane, wid); __syncthreads();
    layer_fwd<8, 0>(xb1, xb0, W + 51200, b7, lane, wid); __syncthreads();

    // layer 8: N=257 (17 n-tiles), no activation, f32 store. Wave 0 carries tile 16.
    {
        const bf16x8* wl = W + 59392;
        const int prow = lane & 15;
        const int kg   = (lane >> 4) << 3;
        const int rb4  = (lane >> 4) << 2;
        f32x4 acc[4][2] = {};
        f32x4 acc2[4]   = {};
#pragma unroll 2
        for (int ks = 0; ks < 8; ++ks) {
            bf16x8 a[2], b[4];
#pragma unroll
            for (int nii = 0; nii < 2; ++nii)
                a[nii] = wl[((wid * 2 + nii) * 8 + ks) * 64 + lane];
            bf16x8 a2;
            if (wid == 0) a2 = wl[(128 + ks) * 64 + lane];
#pragma unroll
            for (int mi = 0; mi < 4; ++mi)
                b[mi] = *(const bf16x8*)xaddrc(xb0, mi * 16 + prow, ks * 32 + kg);
#pragma unroll
            for (int mi = 0; mi < 4; ++mi) {
#pragma unroll
                for (int nii = 0; nii < 2; ++nii)
                    acc[mi][nii] = __builtin_amdgcn_mfma_f32_16x16x32_bf16(
                        a[nii], b[mi], acc[mi][nii], 0, 0, 0);
            }
            if (wid == 0) {
#pragma unroll
                for (int mi = 0; mi < 4; ++mi)
                    acc2[mi] = __builtin_amdgcn_mfma_f32_16x16x32_bf16(
                        a2, b[mi], acc2[mi], 0, 0, 0);
            }
        }
#pragma unroll
        for (int nii = 0; nii < 2; ++nii) {
            const int cb = (wid * 2 + nii) * 16 + rb4;          // <= 252
            const f32x4 bv = *(const f32x4*)(b8 + cb);
#pragma unroll
            for (int mi = 0; mi < 4; ++mi) {
                const int rowoff = (pt0 + mi * 16 + prow) * 257 + cb;
#pragma unroll
                for (int r = 0; r < 4; ++r)
                    out[rowoff + r] = acc[mi][nii][r] + bv[r];
            }
        }
        if (wid == 0 && rb4 == 0) {
            const float blast = b8[256];
#pragma unroll
            for (int mi = 0; mi < 4; ++mi)
                out[(pt0 + mi * 16 + prow) * 257 + 256] = acc2[mi][0] + blast;
        }
    }
}

extern "C" void kernel_launch(void* const* d_in, const int* in_sizes, int n_in,
                              void* d_out, int out_size, void* d_ws, size_t ws_size,
                              hipStream_t stream)
{
    const float* xin  = (const float*)d_in[0];
    const float* cond = (const float*)d_in[1];
    const float* Wp[9]; const float* bp[9];
    for (int l = 0; l < 9; ++l) { Wp[l] = (const float*)d_in[2 + 2 * l]; bp[l] = (const float*)d_in[3 + 2 * l]; }
    short* wbf = (short*)d_ws;   // needs 1,089,536 B

    prep_kernel<<<dim3(266), dim3(256), 0, stream>>>(
        Wp[0], Wp[1], Wp[2], Wp[3], Wp[4], Wp[5], Wp[6], Wp[7], Wp[8], wbf);
    net_kernel<<<dim3(3125), dim3(512), 0, stream>>>(
        xin, cond, (const bf16x8*)wbf,
        bp[0], bp[1], bp[2], bp[3], bp[4], bp[5], bp[6], bp[7], bp[8],
        (float*)d_out);
}